// Round 1
// baseline (3189.378 us; speedup 1.0000x reference)
//
#include <hip/hip_runtime.h>

#define N_USERS 100000
#define N_ITEMS 50000
#define N_NODES 150000
#define EMBED 64
#define N_LAYERS 3

// ---------------------------------------------------------------------------
// init: ego0 = concat(u_emb + u_emb_pre, i_emb + i_emb_pre); acc = ego0
// float4-vectorized over N_NODES*EMBED elements.
// ---------------------------------------------------------------------------
__global__ void lgcn_init(const float* __restrict__ u, const float* __restrict__ it,
                          const float* __restrict__ up, const float* __restrict__ ip,
                          float* __restrict__ ego, float* __restrict__ acc) {
    int idx = blockIdx.x * blockDim.x + threadIdx.x;  // float4 index
    const int total = N_NODES * EMBED / 4;
    if (idx >= total) return;
    const int uCount = N_USERS * EMBED / 4;
    float4 v;
    if (idx < uCount) {
        float4 a = reinterpret_cast<const float4*>(u)[idx];
        float4 b = reinterpret_cast<const float4*>(up)[idx];
        v = make_float4(a.x + b.x, a.y + b.y, a.z + b.z, a.w + b.w);
    } else {
        int j = idx - uCount;
        float4 a = reinterpret_cast<const float4*>(it)[j];
        float4 b = reinterpret_cast<const float4*>(ip)[j];
        v = make_float4(a.x + b.x, a.y + b.y, a.z + b.z, a.w + b.w);
    }
    reinterpret_cast<float4*>(ego)[idx] = v;
    reinterpret_cast<float4*>(acc)[idx] = v;
}

// ---------------------------------------------------------------------------
// SpMM scatter: 64 threads per edge, one float per thread.
// y[rows[e]][lane] += vals[e] * x[cols[e]][lane]   (atomic)
// Consecutive threads cover one edge's 64 floats -> coalesced gather and
// coalesced atomic segment.
// ---------------------------------------------------------------------------
__global__ void lgcn_spmm_scatter(const int* __restrict__ rows,
                                  const int* __restrict__ cols,
                                  const float* __restrict__ vals,
                                  const float* __restrict__ x,
                                  float* __restrict__ y, int nnz) {
    long long tid = (long long)blockIdx.x * blockDim.x + threadIdx.x;
    int e = (int)(tid >> 6);
    if (e >= nnz) return;
    int lane = (int)(tid & 63);
    int r = rows[e];
    int c = cols[e];
    float v = vals[e];
    float xv = x[(long long)c * EMBED + lane];
    atomicAdd(&y[(long long)r * EMBED + lane], v * xv);
}

// ---------------------------------------------------------------------------
// acc = (acc + ego) * scale   (scale = 1 for layers 0,1; 0.25 fused on last)
// ---------------------------------------------------------------------------
__global__ void lgcn_add_scale(float* __restrict__ acc, const float* __restrict__ ego,
                               float scale) {
    int idx = blockIdx.x * blockDim.x + threadIdx.x;
    const int total = N_NODES * EMBED / 4;
    if (idx >= total) return;
    float4 a = reinterpret_cast<float4*>(acc)[idx];
    float4 e = reinterpret_cast<const float4*>(ego)[idx];
    a.x = (a.x + e.x) * scale;
    a.y = (a.y + e.y) * scale;
    a.z = (a.z + e.z) * scale;
    a.w = (a.w + e.w) * scale;
    reinterpret_cast<float4*>(acc)[idx] = a;
}

extern "C" void kernel_launch(void* const* d_in, const int* in_sizes, int n_in,
                              void* d_out, int out_size, void* d_ws, size_t ws_size,
                              hipStream_t stream) {
    const int*   rows = (const int*)d_in[0];
    const int*   cols = (const int*)d_in[1];
    const float* vals = (const float*)d_in[2];
    const float* u    = (const float*)d_in[3];
    const float* it   = (const float*)d_in[4];
    const float* up   = (const float*)d_in[5];
    const float* ip   = (const float*)d_in[6];
    const int nnz = in_sizes[0];

    float* acc  = (float*)d_out;
    float* ego0 = (float*)d_ws;                          // N_NODES*EMBED floats
    float* ego1 = ego0 + (size_t)N_NODES * EMBED;        // N_NODES*EMBED floats
    const size_t egoBytes = (size_t)N_NODES * EMBED * sizeof(float);

    const int totalVec = N_NODES * EMBED / 4;
    const int tpb = 256;

    lgcn_init<<<(totalVec + tpb - 1) / tpb, tpb, 0, stream>>>(u, it, up, ip, ego0, acc);

    float* cur = ego0;
    float* nxt = ego1;
    for (int l = 0; l < N_LAYERS; ++l) {
        hipMemsetAsync(nxt, 0, egoBytes, stream);
        long long threads = (long long)nnz * 64;
        int blocks = (int)((threads + tpb - 1) / tpb);
        lgcn_spmm_scatter<<<blocks, tpb, 0, stream>>>(rows, cols, vals, cur, nxt, nnz);
        lgcn_add_scale<<<(totalVec + tpb - 1) / tpb, tpb, 0, stream>>>(
            acc, nxt, (l == N_LAYERS - 1) ? (1.0f / (N_LAYERS + 1)) : 1.0f);
        float* t = cur; cur = nxt; nxt = t;
    }
}

// Round 2
// 1256.945 us; speedup vs baseline: 2.5374x; 2.5374x over previous
//
#include <hip/hip_runtime.h>

#define N_USERS 100000
#define N_ITEMS 50000
#define N_NODES 150000
#define EMBED 64
#define N_LAYERS 3

// ---------------------------------------------------------------------------
// init: ego0 = concat(u_emb + u_emb_pre, i_emb + i_emb_pre); acc = ego0
// ---------------------------------------------------------------------------
__global__ void lgcn_init(const float* __restrict__ u, const float* __restrict__ it,
                          const float* __restrict__ up, const float* __restrict__ ip,
                          float* __restrict__ ego, float* __restrict__ acc) {
    int idx = blockIdx.x * blockDim.x + threadIdx.x;  // float4 index
    const int total = N_NODES * EMBED / 4;
    if (idx >= total) return;
    const int uCount = N_USERS * EMBED / 4;
    float4 v;
    if (idx < uCount) {
        float4 a = reinterpret_cast<const float4*>(u)[idx];
        float4 b = reinterpret_cast<const float4*>(up)[idx];
        v = make_float4(a.x + b.x, a.y + b.y, a.z + b.z, a.w + b.w);
    } else {
        int j = idx - uCount;
        float4 a = reinterpret_cast<const float4*>(it)[j];
        float4 b = reinterpret_cast<const float4*>(ip)[j];
        v = make_float4(a.x + b.x, a.y + b.y, a.z + b.z, a.w + b.w);
    }
    reinterpret_cast<float4*>(ego)[idx] = v;
    reinterpret_cast<float4*>(acc)[idx] = v;
}

// ---------------------------------------------------------------------------
// CSR build step 1: histogram of row ids
// ---------------------------------------------------------------------------
__global__ void lgcn_hist(const int* __restrict__ rows, int* __restrict__ counts, int nnz) {
    int e = blockIdx.x * blockDim.x + threadIdx.x;
    if (e < nnz) atomicAdd(&counts[rows[e]], 1);
}

// ---------------------------------------------------------------------------
// CSR build step 2: exclusive scan of counts -> rowptr (and fill cursor copy)
// single workgroup of 1024 threads, iterates over N_NODES in chunks.
// ---------------------------------------------------------------------------
__global__ void lgcn_scan(const int* __restrict__ counts, int* __restrict__ rowptr,
                          int* __restrict__ fill) {
    __shared__ int sm[1024];
    __shared__ int running_s;
    if (threadIdx.x == 0) running_s = 0;
    __syncthreads();
    for (int base = 0; base < N_NODES; base += 1024) {
        int i = base + threadIdx.x;
        int c = (i < N_NODES) ? counts[i] : 0;
        sm[threadIdx.x] = c;
        __syncthreads();
        for (int off = 1; off < 1024; off <<= 1) {
            int t = (threadIdx.x >= (unsigned)off) ? sm[threadIdx.x - off] : 0;
            __syncthreads();
            sm[threadIdx.x] += t;
            __syncthreads();
        }
        int excl = sm[threadIdx.x] - c;
        int r0 = running_s;
        if (i < N_NODES) { rowptr[i] = r0 + excl; fill[i] = r0 + excl; }
        int tot = sm[1023];
        __syncthreads();
        if (threadIdx.x == 0) running_s = r0 + tot;
        __syncthreads();
    }
    if (threadIdx.x == 0) rowptr[N_NODES] = running_s;
}

// ---------------------------------------------------------------------------
// CSR build step 3: scatter (col,val) pairs into row-sorted order
// ---------------------------------------------------------------------------
__global__ void lgcn_scatter_cv(const int* __restrict__ rows, const int* __restrict__ cols,
                                const float* __restrict__ vals, int* __restrict__ fill,
                                int2* __restrict__ cv, int nnz) {
    int e = blockIdx.x * blockDim.x + threadIdx.x;
    if (e >= nnz) return;
    int r = rows[e];
    int pos = atomicAdd(&fill[r], 1);
    cv[pos] = make_int2(cols[e], __float_as_int(vals[e]));
}

// ---------------------------------------------------------------------------
// CSR SpMM, one wave per row, lane = dim. Fused acc update (+ final scale).
//   ego_out[row][lane] = sum_e val_e * x[col_e][lane]
//   acc[row][lane]     = (acc[row][lane] + sum) * scale
// ---------------------------------------------------------------------------
template <bool WRITE_EGO>
__global__ void lgcn_spmm_csr(const int* __restrict__ rowptr, const int2* __restrict__ cv,
                              const float* __restrict__ x, float* __restrict__ ego_out,
                              float* __restrict__ acc, float scale) {
    int row = blockIdx.x * (blockDim.x >> 6) + (threadIdx.x >> 6);
    row = __builtin_amdgcn_readfirstlane(row);   // wave-uniform -> scalar loads
    if (row >= N_NODES) return;
    int lane = threadIdx.x & 63;
    int beg = rowptr[row];
    int end = rowptr[row + 1];
    float s0 = 0.f, s1 = 0.f;
    int e = beg;
    for (; e + 2 <= end; e += 2) {
        int2 p0 = cv[e];
        int2 p1 = cv[e + 1];
        s0 += __int_as_float(p0.y) * x[(size_t)p0.x * EMBED + lane];
        s1 += __int_as_float(p1.y) * x[(size_t)p1.x * EMBED + lane];
    }
    if (e < end) {
        int2 p0 = cv[e];
        s0 += __int_as_float(p0.y) * x[(size_t)p0.x * EMBED + lane];
    }
    float sum = s0 + s1;
    size_t o = (size_t)row * EMBED + lane;
    if (WRITE_EGO) ego_out[o] = sum;
    acc[o] = (acc[o] + sum) * scale;
}

extern "C" void kernel_launch(void* const* d_in, const int* in_sizes, int n_in,
                              void* d_out, int out_size, void* d_ws, size_t ws_size,
                              hipStream_t stream) {
    const int*   rows = (const int*)d_in[0];
    const int*   cols = (const int*)d_in[1];
    const float* vals = (const float*)d_in[2];
    const float* u    = (const float*)d_in[3];
    const float* it   = (const float*)d_in[4];
    const float* up   = (const float*)d_in[5];
    const float* ip   = (const float*)d_in[6];
    const int nnz = in_sizes[0];

    float* acc = (float*)d_out;

    // workspace layout
    float* ego0   = (float*)d_ws;                                  // 38.4 MB
    float* ego1   = ego0 + (size_t)N_NODES * EMBED;                // 38.4 MB
    int*   counts = (int*)(ego1 + (size_t)N_NODES * EMBED);        // 0.6 MB
    int*   fill   = counts + N_NODES;                              // 0.6 MB
    int*   rowptr = fill + N_NODES;                                // N_NODES+1
    int2*  cv     = (int2*)(rowptr + N_NODES + 2);                 // 8B aligned, 38.4 MB

    const int tpb = 256;
    const int totalVec = N_NODES * EMBED / 4;

    lgcn_init<<<(totalVec + tpb - 1) / tpb, tpb, 0, stream>>>(u, it, up, ip, ego0, acc);

    hipMemsetAsync(counts, 0, N_NODES * sizeof(int), stream);
    lgcn_hist<<<(nnz + tpb - 1) / tpb, tpb, 0, stream>>>(rows, counts, nnz);
    lgcn_scan<<<1, 1024, 0, stream>>>(counts, rowptr, fill);
    lgcn_scatter_cv<<<(nnz + tpb - 1) / tpb, tpb, 0, stream>>>(rows, cols, vals, fill, cv, nnz);

    const int rowsPerBlock = tpb / 64;
    const int spmmBlocks = (N_NODES + rowsPerBlock - 1) / rowsPerBlock;

    lgcn_spmm_csr<true><<<spmmBlocks, tpb, 0, stream>>>(rowptr, cv, ego0, ego1, acc, 1.0f);
    lgcn_spmm_csr<true><<<spmmBlocks, tpb, 0, stream>>>(rowptr, cv, ego1, ego0, acc, 1.0f);
    lgcn_spmm_csr<false><<<spmmBlocks, tpb, 0, stream>>>(rowptr, cv, ego0, nullptr, acc,
                                                         1.0f / (N_LAYERS + 1));
}

// Round 3
// 1106.382 us; speedup vs baseline: 2.8827x; 1.1361x over previous
//
#include <hip/hip_runtime.h>

#define N_USERS 100000
#define N_ITEMS 50000
#define N_NODES 150000
#define EMBED 64
#define N_LAYERS 3

#define BUCKET_SHIFT 10
#define BUCKET_ROWS 1024
#define N_BUCKETS ((N_NODES + BUCKET_ROWS - 1) / BUCKET_ROWS)   // 147
#define PASSA_CHUNK 16384

// ---------------------------------------------------------------------------
// init: ego0 = concat(u_emb + u_emb_pre, i_emb + i_emb_pre); acc = ego0
// ---------------------------------------------------------------------------
__global__ void lgcn_init(const float* __restrict__ u, const float* __restrict__ it,
                          const float* __restrict__ up, const float* __restrict__ ip,
                          float* __restrict__ ego, float* __restrict__ acc) {
    int idx = blockIdx.x * blockDim.x + threadIdx.x;  // float4 index
    const int total = N_NODES * EMBED / 4;
    if (idx >= total) return;
    const int uCount = N_USERS * EMBED / 4;
    float4 v;
    if (idx < uCount) {
        float4 a = reinterpret_cast<const float4*>(u)[idx];
        float4 b = reinterpret_cast<const float4*>(up)[idx];
        v = make_float4(a.x + b.x, a.y + b.y, a.z + b.z, a.w + b.w);
    } else {
        int j = idx - uCount;
        float4 a = reinterpret_cast<const float4*>(it)[j];
        float4 b = reinterpret_cast<const float4*>(ip)[j];
        v = make_float4(a.x + b.x, a.y + b.y, a.z + b.z, a.w + b.w);
    }
    reinterpret_cast<float4*>(ego)[idx] = v;
    reinterpret_cast<float4*>(acc)[idx] = v;
}

// ---------------------------------------------------------------------------
// row histogram
// ---------------------------------------------------------------------------
__global__ void lgcn_hist(const int* __restrict__ rows, int* __restrict__ counts, int nnz) {
    int e = blockIdx.x * blockDim.x + threadIdx.x;
    if (e < nnz) atomicAdd(&counts[rows[e]], 1);
}

// ---------------------------------------------------------------------------
// bucket counts = reduction of row counts over each 1024-row bucket
// ---------------------------------------------------------------------------
__global__ void lgcn_bucket_cnt(const int* __restrict__ counts, int* __restrict__ bucketCnt) {
    __shared__ int sm[256];
    int b = blockIdx.x;
    int base = b * BUCKET_ROWS;
    int s = 0;
    for (int i = threadIdx.x; i < BUCKET_ROWS; i += 256) {
        int idx = base + i;
        if (idx < N_NODES) s += counts[idx];
    }
    sm[threadIdx.x] = s;
    __syncthreads();
    for (int off = 128; off > 0; off >>= 1) {
        if (threadIdx.x < (unsigned)off) sm[threadIdx.x] += sm[threadIdx.x + off];
        __syncthreads();
    }
    if (threadIdx.x == 0) bucketCnt[b] = sm[0];
}

// ---------------------------------------------------------------------------
// exclusive scan of bucket counts (N_BUCKETS <= 256), one block
// ---------------------------------------------------------------------------
__global__ void lgcn_bucket_scan(const int* __restrict__ bucketCnt, int* __restrict__ bucketBase,
                                 int* __restrict__ bucketFill, int* __restrict__ rowptr) {
    __shared__ int sm[256];
    int c = (threadIdx.x < N_BUCKETS) ? bucketCnt[threadIdx.x] : 0;
    sm[threadIdx.x] = c;
    __syncthreads();
    for (int off = 1; off < 256; off <<= 1) {
        int t = (threadIdx.x >= (unsigned)off) ? sm[threadIdx.x - off] : 0;
        __syncthreads();
        sm[threadIdx.x] += t;
        __syncthreads();
    }
    int excl = sm[threadIdx.x] - c;
    if (threadIdx.x < N_BUCKETS) { bucketBase[threadIdx.x] = excl; bucketFill[threadIdx.x] = excl; }
    if (threadIdx.x == N_BUCKETS - 1) rowptr[N_NODES] = sm[threadIdx.x];
}

// ---------------------------------------------------------------------------
// per-bucket row scan: rowptr[i] = bucketBase[b] + exclusive_scan(counts within bucket)
// ---------------------------------------------------------------------------
__global__ void lgcn_row_scan(const int* __restrict__ counts, const int* __restrict__ bucketBase,
                              int* __restrict__ rowptr, int* __restrict__ fill) {
    __shared__ int sm[BUCKET_ROWS];
    int b = blockIdx.x;
    int i = b * BUCKET_ROWS + threadIdx.x;
    int c = (i < N_NODES) ? counts[i] : 0;
    sm[threadIdx.x] = c;
    __syncthreads();
    for (int off = 1; off < BUCKET_ROWS; off <<= 1) {
        int t = (threadIdx.x >= (unsigned)off) ? sm[threadIdx.x - off] : 0;
        __syncthreads();
        sm[threadIdx.x] += t;
        __syncthreads();
    }
    if (i < N_NODES) {
        int v = bucketBase[b] + sm[threadIdx.x] - c;
        rowptr[i] = v;
        fill[i] = v;
    }
}

// ---------------------------------------------------------------------------
// Pass A: partition edges into bucket-contiguous (row,col,val) arrays.
// Per-WG LDS histogram -> one global cursor reservation per bucket -> scatter
// into contiguous runs.
// ---------------------------------------------------------------------------
__global__ void lgcn_partition(const int* __restrict__ rows, const int* __restrict__ cols,
                               const float* __restrict__ vals, int* __restrict__ bucketFill,
                               int* __restrict__ br, int* __restrict__ bc,
                               float* __restrict__ bv, int nnz) {
    __shared__ int lcnt[N_BUCKETS];
    __shared__ int lbase[N_BUCKETS];
    int chunk0 = blockIdx.x * PASSA_CHUNK;
    for (int b = threadIdx.x; b < N_BUCKETS; b += blockDim.x) lcnt[b] = 0;
    __syncthreads();
    int end = min(chunk0 + PASSA_CHUNK, nnz);
    for (int e = chunk0 + threadIdx.x; e < end; e += blockDim.x) {
        int r = rows[e];
        atomicAdd(&lcnt[r >> BUCKET_SHIFT], 1);
    }
    __syncthreads();
    for (int b = threadIdx.x; b < N_BUCKETS; b += blockDim.x) {
        int c = lcnt[b];
        lbase[b] = c ? atomicAdd(&bucketFill[b], c) : 0;
        lcnt[b] = 0;  // reuse as intra-WG cursor
    }
    __syncthreads();
    for (int e = chunk0 + threadIdx.x; e < end; e += blockDim.x) {
        int r = rows[e];
        int b = r >> BUCKET_SHIFT;
        int pos = lbase[b] + atomicAdd(&lcnt[b], 1);
        br[pos] = r;
        bc[pos] = cols[e];
        bv[pos] = vals[e];
    }
}

// ---------------------------------------------------------------------------
// Pass B: scatter (col,val) to exact row-sorted position. Input is
// bucket-sorted, so concurrent writes stay within a few buckets' windows.
// ---------------------------------------------------------------------------
__global__ void lgcn_scatter_cv(const int* __restrict__ br, const int* __restrict__ bc,
                                const float* __restrict__ bv, int* __restrict__ fill,
                                int2* __restrict__ cv, int nnz) {
    int e = blockIdx.x * blockDim.x + threadIdx.x;
    if (e >= nnz) return;
    int r = br[e];
    int pos = atomicAdd(&fill[r], 1);
    cv[pos] = make_int2(bc[e], __float_as_int(bv[e]));
}

// ---------------------------------------------------------------------------
// CSR SpMM, one wave per row, lane = dim. Fused acc update (+ final scale).
// ---------------------------------------------------------------------------
template <bool WRITE_EGO>
__global__ void lgcn_spmm_csr(const int* __restrict__ rowptr, const int2* __restrict__ cv,
                              const float* __restrict__ x, float* __restrict__ ego_out,
                              float* __restrict__ acc, float scale) {
    int row = blockIdx.x * (blockDim.x >> 6) + (threadIdx.x >> 6);
    row = __builtin_amdgcn_readfirstlane(row);   // wave-uniform -> scalar loads
    if (row >= N_NODES) return;
    int lane = threadIdx.x & 63;
    int beg = rowptr[row];
    int end = rowptr[row + 1];
    float s0 = 0.f, s1 = 0.f;
    int e = beg;
    for (; e + 2 <= end; e += 2) {
        int2 p0 = cv[e];
        int2 p1 = cv[e + 1];
        s0 += __int_as_float(p0.y) * x[(size_t)p0.x * EMBED + lane];
        s1 += __int_as_float(p1.y) * x[(size_t)p1.x * EMBED + lane];
    }
    if (e < end) {
        int2 p0 = cv[e];
        s0 += __int_as_float(p0.y) * x[(size_t)p0.x * EMBED + lane];
    }
    float sum = s0 + s1;
    size_t o = (size_t)row * EMBED + lane;
    if (WRITE_EGO) ego_out[o] = sum;
    acc[o] = (acc[o] + sum) * scale;
}

extern "C" void kernel_launch(void* const* d_in, const int* in_sizes, int n_in,
                              void* d_out, int out_size, void* d_ws, size_t ws_size,
                              hipStream_t stream) {
    const int*   rows = (const int*)d_in[0];
    const int*   cols = (const int*)d_in[1];
    const float* vals = (const float*)d_in[2];
    const float* u    = (const float*)d_in[3];
    const float* it   = (const float*)d_in[4];
    const float* up   = (const float*)d_in[5];
    const float* ip   = (const float*)d_in[6];
    const int nnz = in_sizes[0];

    float* acc = (float*)d_out;

    // workspace layout
    float* ego0       = (float*)d_ws;                              // 38.4 MB
    float* ego1       = ego0 + (size_t)N_NODES * EMBED;            // 38.4 MB
    int*   counts     = (int*)(ego1 + (size_t)N_NODES * EMBED);    // 0.6 MB
    int*   fill       = counts + N_NODES;                          // 0.6 MB
    int*   rowptr     = fill + N_NODES;                            // N_NODES+1
    int*   bucketCnt  = rowptr + N_NODES + 1;                      // 147
    int*   bucketBase = bucketCnt + N_BUCKETS;                     // 147
    int*   bucketFill = bucketBase + N_BUCKETS;                    // 147
    int*   pad        = bucketFill + N_BUCKETS;
    size_t off        = ((size_t)(pad - (int*)d_ws) + 3) & ~(size_t)3;  // 16B align
    int2*  cv         = (int2*)((int*)d_ws + off);                 // 38.4 MB
    int*   br         = (int*)(cv + nnz);                          // 19.2 MB
    int*   bc         = br + nnz;                                  // 19.2 MB
    float* bv         = (float*)(bc + nnz);                        // 19.2 MB

    const int tpb = 256;
    const int totalVec = N_NODES * EMBED / 4;

    lgcn_init<<<(totalVec + tpb - 1) / tpb, tpb, 0, stream>>>(u, it, up, ip, ego0, acc);

    hipMemsetAsync(counts, 0, N_NODES * sizeof(int), stream);
    lgcn_hist<<<(nnz + tpb - 1) / tpb, tpb, 0, stream>>>(rows, counts, nnz);
    lgcn_bucket_cnt<<<N_BUCKETS, 256, 0, stream>>>(counts, bucketCnt);
    lgcn_bucket_scan<<<1, 256, 0, stream>>>(bucketCnt, bucketBase, bucketFill, rowptr);
    lgcn_row_scan<<<N_BUCKETS, BUCKET_ROWS, 0, stream>>>(counts, bucketBase, rowptr, fill);
    lgcn_partition<<<(nnz + PASSA_CHUNK - 1) / PASSA_CHUNK, tpb, 0, stream>>>(
        rows, cols, vals, bucketFill, br, bc, bv, nnz);
    lgcn_scatter_cv<<<(nnz + tpb - 1) / tpb, tpb, 0, stream>>>(br, bc, bv, fill, cv, nnz);

    const int rowsPerBlock = tpb / 64;
    const int spmmBlocks = (N_NODES + rowsPerBlock - 1) / rowsPerBlock;

    lgcn_spmm_csr<true><<<spmmBlocks, tpb, 0, stream>>>(rowptr, cv, ego0, ego1, acc, 1.0f);
    lgcn_spmm_csr<true><<<spmmBlocks, tpb, 0, stream>>>(rowptr, cv, ego1, ego0, acc, 1.0f);
    lgcn_spmm_csr<false><<<spmmBlocks, tpb, 0, stream>>>(rowptr, cv, ego0, nullptr, acc,
                                                         1.0f / (N_LAYERS + 1));
}